// Round 5
// baseline (504.301 us; speedup 1.0000x reference)
//
#include <hip/hip_runtime.h>
#include <cstdint>
#include <cstddef>

typedef _Float16 f16;
typedef _Float16 f16x4 __attribute__((ext_vector_type(4)));
typedef _Float16 f16x8 __attribute__((ext_vector_type(8)));
typedef float f32x4 __attribute__((ext_vector_type(4)));

#define LRELU_SLOPE 0.2f

#define GLL16(g, l)                                                          \
  __builtin_amdgcn_global_load_lds(                                          \
      (const __attribute__((address_space(1))) void*)(g),                    \
      (__attribute__((address_space(3))) void*)(l), 16, 0, 0)

// ---------------- prep: x (f32) -> x_h (f16), padded rows zeroed ----------------
__global__ __launch_bounds__(256) void k_prep_xh(const float* __restrict__ x,
                                                 f16* __restrict__ xh,
                                                 int nvalid, int npad) {
  int total = npad * 192;
  for (int idx = blockIdx.x * blockDim.x + threadIdx.x; idx < total;
       idx += gridDim.x * blockDim.x) {
    int row = idx / 192;
    f16x4 o;
    if (row < nvalid) {
      const float4 v = *(const float4*)(x + (size_t)idx * 4);
      o[0] = (f16)v.x; o[1] = (f16)v.y; o[2] = (f16)v.z; o[3] = (f16)v.w;
    } else {
      o[0] = (f16)0.f; o[1] = (f16)0.f; o[2] = (f16)0.f; o[3] = (f16)0.f;
    }
    *(f16x4*)(xh + (size_t)idx * 4) = o;
  }
}

// ---------------- W [768][768] f32 -> Wt [n][k] f16 (transposed) ----------------
__global__ __launch_bounds__(256) void k_transpose_w(const float* __restrict__ W,
                                                     f16* __restrict__ Wt) {
  __shared__ float tile[32][33];
  int bn = blockIdx.x * 32;
  int bk = blockIdx.y * 32;
  int tx = threadIdx.x & 31, ty = threadIdx.x >> 5;
  #pragma unroll
  for (int r = ty; r < 32; r += 8)
    tile[r][tx] = W[(size_t)(bk + r) * 768 + bn + tx];
  __syncthreads();
  #pragma unroll
  for (int r = ty; r < 32; r += 8)
    Wt[(size_t)(bn + r) * 768 + bk + tx] = (f16)tile[tx][r];
}

// ---------------- CSR build ----------------
__global__ void k_zero_ints(int* __restrict__ p, int n) {
  for (int i = blockIdx.x * blockDim.x + threadIdx.x; i < n;
       i += gridDim.x * blockDim.x) p[i] = 0;
}

__global__ void k_hist(const int* __restrict__ dst, int E, int* __restrict__ counts) {
  for (int e = blockIdx.x * blockDim.x + threadIdx.x; e < E;
       e += gridDim.x * blockDim.x) atomicAdd(&counts[dst[e]], 1);
}

__global__ __launch_bounds__(1024) void k_scan_block(const int* __restrict__ counts,
                                                     int* __restrict__ starts,
                                                     int* __restrict__ cursor, int n) {
  const int t = threadIdx.x;
  const int nthr = 1024;
  const int chunk = (n + nthr - 1) / nthr;
  const int base = t * chunk;
  int tsum = 0;
  for (int i = 0; i < chunk; i++) {
    int idx = base + i;
    if (idx < n) tsum += counts[idx];
  }
  int lane = t & 63, wv = t >> 6;
  int s = tsum;
  #pragma unroll
  for (int off = 1; off < 64; off <<= 1) {
    int tmp = __shfl_up(s, off);
    if (lane >= off) s += tmp;
  }
  __shared__ int wsum[16];
  if (lane == 63) wsum[wv] = s;
  __syncthreads();
  int woff = 0;
  for (int w = 0; w < wv; w++) woff += wsum[w];
  int run = woff + s - tsum;
  for (int i = 0; i < chunk; i++) {
    int idx = base + i;
    if (idx < n) {
      starts[idx] = run;
      cursor[idx] = run;
      run += counts[idx];
    }
  }
  if (t == nthr - 1) starts[n] = run;
}

__global__ void k_fill(const int* __restrict__ src, const int* __restrict__ dst, int E,
                       int* __restrict__ cursor, int* __restrict__ src_sorted,
                       int* __restrict__ dst_sorted) {
  for (int e = blockIdx.x * blockDim.x + threadIdx.x; e < E;
       e += gridDim.x * blockDim.x) {
    int slot = atomicAdd(&cursor[dst[e]], 1);
    src_sorted[slot] = src[e];
    dst_sorted[slot] = dst[e];
  }
}

// ---------------- fp16 MFMA GEMM, global_load_lds staging, slice-major C ---------
// LDS: [128 rows][4 slots][8 f16]; slot = kc ^ ((row>>1)&3) (bank swizzle).
// C layout: [8 slices][Mpad][96] f16 (slice = col/96), SS = slice stride.
__global__ __launch_bounds__(256) void k_gemm_f16(const f16* __restrict__ A,
                                                  const f16* __restrict__ Bt,
                                                  f16* __restrict__ C, int Mvalid,
                                                  int SS) {
  __shared__ __align__(16) f16 As[4096];
  __shared__ __align__(16) f16 Bs[4096];
  const int K = 768;
  const int tid = threadIdx.x;
  const int bm = blockIdx.x * 128;
  const int bn = blockIdx.y * 128;
  const int lane = tid & 63;
  const int wave = tid >> 6;
  const int wr = (wave >> 1) * 64;
  const int wc = (wave & 1) * 64;

  const int r0 = tid >> 2;
  const int kc = (tid & 3) ^ ((r0 >> 1) & 3);
  const size_t offA0 = (size_t)(bm + r0) * K + kc * 8;
  const size_t offB0 = (size_t)(bn + r0) * K + kc * 8;
  f16* ldsA0 = As + wave * 512;
  f16* ldsA1 = As + 2048 + wave * 512;
  f16* ldsB0 = Bs + wave * 512;
  f16* ldsB1 = Bs + 2048 + wave * 512;

  f32x4 acc[4][4];
  const f32x4 vzero = {0.f, 0.f, 0.f, 0.f};
  #pragma unroll
  for (int i = 0; i < 4; i++)
    #pragma unroll
    for (int j = 0; j < 4; j++) acc[i][j] = vzero;

  const int fr = lane & 15;
  const int fq = lane >> 4;

  for (int k0 = 0; k0 < K; k0 += 32) {
    GLL16(A + offA0 + k0, ldsA0);
    GLL16(A + offA0 + (size_t)64 * K + k0, ldsA1);
    GLL16(Bt + offB0 + k0, ldsB0);
    GLL16(Bt + offB0 + (size_t)64 * K + k0, ldsB1);
    __syncthreads();
    f16x8 af[4], bf[4];
    #pragma unroll
    for (int i = 0; i < 4; i++) {
      const int r = wr + i * 16 + fr;
      const int slot = fq ^ ((r >> 1) & 3);
      af[i] = *(const f16x8*)(&As[r * 32 + slot * 8]);
    }
    #pragma unroll
    for (int j = 0; j < 4; j++) {
      const int r = wc + j * 16 + fr;
      const int slot = fq ^ ((r >> 1) & 3);
      bf[j] = *(const f16x8*)(&Bs[r * 32 + slot * 8]);
    }
    #pragma unroll
    for (int i = 0; i < 4; i++)
      #pragma unroll
      for (int j = 0; j < 4; j++)
        acc[i][j] = __builtin_amdgcn_mfma_f32_16x16x32_f16(af[i], bf[j], acc[i][j], 0, 0, 0);
    __syncthreads();
  }

  #pragma unroll
  for (int i = 0; i < 4; i++) {
    #pragma unroll
    for (int j = 0; j < 4; j++) {
      const int col = bn + wc + j * 16 + fr;
      const int cs = col / 96;
      const int cw = col - cs * 96;
      f16* cp = C + (size_t)cs * SS + cw;
      #pragma unroll
      for (int r = 0; r < 4; r++) {
        const int row = bm + wr + i * 16 + fq * 4 + r;
        if (row < Mvalid) cp[(size_t)row * 96] = (f16)acc[i][j][r];
      }
    }
  }
}

// ---------------- attention logits from slice-major h ----------------
template <int H>
__global__ __launch_bounds__(256) void k_al(const f16* __restrict__ hs,
                                            const float* __restrict__ a_src,
                                            const float* __restrict__ a_dst,
                                            float* __restrict__ als,
                                            float* __restrict__ ald, int N, int SS) {
  int node = blockIdx.x * 4 + (threadIdx.x >> 6);
  int lane = threadIdx.x & 63;
  if (node >= N) return;
  const int sl = lane >> 3, wl = lane & 7;
  const f16* hp = hs + (size_t)sl * SS + (size_t)node * 96 + wl * 12;
  float ss = 0.f, sd = 0.f;
  const int cbase = sl * 96 + wl * 12;
  #pragma unroll
  for (int q = 0; q < 3; q++) {
    f16x4 hv = *(const f16x4*)(hp + q * 4);
    #pragma unroll
    for (int j = 0; j < 4; j++) {
      int c = cbase + q * 4 + j;
      float v = (float)hv[j];
      ss += v * a_src[c];
      sd += v * a_dst[c];
    }
  }
  const int red = (H == 8) ? 8 : 64;
  #pragma unroll
  for (int off = 1; off < red; off <<= 1) {
    ss += __shfl_xor(ss, off);
    sd += __shfl_xor(sd, off);
  }
  if (H == 8) {
    if ((lane & 7) == 0) {
      als[(size_t)node * 8 + sl] = ss;
      ald[(size_t)node * 8 + sl] = sd;
    }
  } else {
    if (lane == 0) { als[node] = ss; ald[node] = sd; }
  }
}

// ---------------- edge-parallel exp(leaky_relu(logit)), head-major ex[H][E] ------
template <int H>
__global__ __launch_bounds__(256) void k_alpha(const float* __restrict__ als,
                                               const float* __restrict__ ald,
                                               const int* __restrict__ srcs,
                                               const int* __restrict__ dsts,
                                               float* __restrict__ ex, int E) {
  const int e = blockIdx.x * 256 + threadIdx.x;
  if (e >= E) return;
  const int s = srcs[e], d = dsts[e];
  #pragma unroll
  for (int h = 0; h < H; h++) {
    float v = als[(size_t)s * H + h] + ald[(size_t)d * H + h];
    v = v > 0.f ? v : LRELU_SLOPE * v;
    ex[(size_t)h * E + e] = __expf(v);
  }
}

// ---------------- slice-gather aggregation: block = (node, slice) ----------------
// bid = n*8 + s -> slice s pinned to XCD s (round-robin); per-XCD working set =
// one 3.84 MB h-slice (L2-resident) + its 1.4 MB ex plane (streamed once).
// 192 threads = 8 edge-lanes x 24 ch-lanes; uniform control flow (one node/block);
// z falls out of the ex loads; LDS reduce across edge-lanes.
template <int H, bool FINAL>
__global__ __launch_bounds__(192) void k_agg2(
    const f16* __restrict__ hs, const float* __restrict__ ex,
    const int* __restrict__ starts, const int* __restrict__ srcs,
    const float* __restrict__ bias, void* __restrict__ outv,
    int N, int SS, int E) {
  const int s = blockIdx.x & 7;
  const int n = blockIdx.x >> 3;
  const int t = threadIdx.x;
  const int k = t / 24;        // edge-lane 0..7
  const int c = t - k * 24;    // ch-lane 0..23
  const int head = (H == 8) ? s : 0;
  const int start = starts[n];
  const int deg = starts[n + 1] - start;
  const f16* hsl = hs + (size_t)s * SS;
  const float* exp_ = ex + (size_t)head * E;

  float4 acc = {0.f, 0.f, 0.f, 0.f};
  float z = 0.f;
  for (int i = k; i < deg; i += 8) {
    const int slot = start + i;
    const float a = exp_[slot];
    const int sv = srcs[slot];
    const f16x4 hv = *(const f16x4*)(hsl + (size_t)sv * 96 + c * 4);
    z += a;
    acc.x += a * (float)hv[0];
    acc.y += a * (float)hv[1];
    acc.z += a * (float)hv[2];
    acc.w += a * (float)hv[3];
  }

  __shared__ float s_acc[8][96];
  __shared__ float s_z[8];
  *(float4*)&s_acc[k][c * 4] = acc;
  if (c == 0) s_z[k] = z;
  __syncthreads();

  if (t < 96) {
    float v = 0.f;
    #pragma unroll
    for (int kk = 0; kk < 8; kk++) v += s_acc[kk][t];
    float zt = 0.f;
    #pragma unroll
    for (int kk = 0; kk < 8; kk++) zt += s_z[kk];
    const float inv = 1.f / (zt + 1e-16f);
    float o = v * inv + bias[s * 96 + t];
    if (FINAL) {
      ((float*)outv)[(size_t)n * 768 + s * 96 + t] = o;
    } else {
      o = o > 0.f ? o : expm1f(o);
      ((f16*)outv)[(size_t)n * 768 + s * 96 + t] = (f16)o;
    }
  }
}

// ---------------- launcher ----------------
extern "C" void kernel_launch(void* const* d_in, const int* in_sizes, int n_in,
                              void* d_out, int out_size, void* d_ws, size_t ws_size,
                              hipStream_t stream) {
  const float* x   = (const float*)d_in[0];
  const int*   ei  = (const int*)d_in[1];
  const float* W1  = (const float*)d_in[2];
  const float* as1 = (const float*)d_in[3];
  const float* ad1 = (const float*)d_in[4];
  const float* b1  = (const float*)d_in[5];
  const float* W2  = (const float*)d_in[6];
  const float* as2 = (const float*)d_in[7];
  const float* ad2 = (const float*)d_in[8];
  const float* b2  = (const float*)d_in[9];

  const int N = in_sizes[0] / 768;
  const int E = in_sizes[1] / 2;
  const int Mpad = (N + 127) & ~127;
  const int SS = Mpad * 96;  // slice stride (elements)
  const int* srcp = ei;
  const int* dstp = ei + E;

  char* p = (char*)d_ws;
  auto alloc = [&](size_t b) { char* r = p; p += (b + 255) & ~(size_t)255; return r; };
  f16*   bufX   = (f16*)alloc((size_t)Mpad * 768 * sizeof(f16));  // x_h, then out1
  f16*   bufH   = (f16*)alloc((size_t)Mpad * 768 * sizeof(f16));  // h1/h2 slice-major
  f16*   Wt1    = (f16*)alloc((size_t)768 * 768 * sizeof(f16));
  f16*   Wt2    = (f16*)alloc((size_t)768 * 768 * sizeof(f16));
  float* ex     = (float*)alloc((size_t)8 * E * sizeof(float));   // head-major ex
  float* als1   = (float*)alloc((size_t)N * 8 * sizeof(float));
  float* ald1   = (float*)alloc((size_t)N * 8 * sizeof(float));
  float* als2   = (float*)alloc((size_t)N * sizeof(float));
  float* ald2   = (float*)alloc((size_t)N * sizeof(float));
  int*   counts = (int*)alloc((size_t)N * sizeof(int));
  int*   starts = (int*)alloc(((size_t)N + 1) * sizeof(int));
  int*   cursor = (int*)alloc((size_t)N * sizeof(int));
  int*   srcs   = (int*)alloc((size_t)E * sizeof(int));
  int*   dsts   = (int*)alloc((size_t)E * sizeof(int));

  // CSR build (shared by both layers)
  k_zero_ints<<<dim3(80), dim3(256), 0, stream>>>(counts, N);
  k_hist<<<dim3(512), dim3(256), 0, stream>>>(dstp, E, counts);
  k_scan_block<<<dim3(1), dim3(1024), 0, stream>>>(counts, starts, cursor, N);
  k_fill<<<dim3(512), dim3(256), 0, stream>>>(srcp, dstp, E, cursor, srcs, dsts);

  // prep
  k_prep_xh<<<dim3(1024), dim3(256), 0, stream>>>(x, bufX, N, Mpad);
  k_transpose_w<<<dim3(24, 24), dim3(256), 0, stream>>>(W1, Wt1);
  k_transpose_w<<<dim3(24, 24), dim3(256), 0, stream>>>(W2, Wt2);

  const int eb = (E + 255) / 256;

  // layer 1
  k_gemm_f16<<<dim3(Mpad / 128, 6), dim3(256), 0, stream>>>(bufX, Wt1, bufH, N, SS);
  k_al<8><<<dim3((N + 3) / 4), dim3(256), 0, stream>>>(bufH, as1, ad1, als1, ald1, N, SS);
  k_alpha<8><<<dim3(eb), dim3(256), 0, stream>>>(als1, ald1, srcs, dsts, ex, E);
  k_agg2<8, false><<<dim3(N * 8), dim3(192), 0, stream>>>(
      bufH, ex, starts, srcs, b1, bufX, N, SS, E);

  // layer 2 (bufX pad rows still hold k_prep_xh zeros)
  k_gemm_f16<<<dim3(Mpad / 128, 6), dim3(256), 0, stream>>>(bufX, Wt2, bufH, N, SS);
  k_al<1><<<dim3((N + 3) / 4), dim3(256), 0, stream>>>(bufH, as2, ad2, als2, ald2, N, SS);
  k_alpha<1><<<dim3(eb), dim3(256), 0, stream>>>(als2, ald2, srcs, dsts, ex, E);
  k_agg2<1, true><<<dim3(N * 8), dim3(192), 0, stream>>>(
      bufH, ex, starts, srcs, b2, d_out, N, SS, E);
}

// Round 6
// 340.152 us; speedup vs baseline: 1.4826x; 1.4826x over previous
//
#include <hip/hip_runtime.h>
#include <cstdint>
#include <cstddef>

typedef _Float16 f16;
typedef _Float16 f16x4 __attribute__((ext_vector_type(4)));
typedef _Float16 f16x8 __attribute__((ext_vector_type(8)));
typedef float f32x4 __attribute__((ext_vector_type(4)));

#define LRELU_SLOPE 0.2f

#define GLL16(g, l)                                                          \
  __builtin_amdgcn_global_load_lds(                                          \
      (const __attribute__((address_space(1))) void*)(g),                    \
      (__attribute__((address_space(3))) void*)(l), 16, 0, 0)

// ---------------- prep: x (f32) -> x_h (f16), padded rows zeroed ----------------
__global__ __launch_bounds__(256) void k_prep_xh(const float* __restrict__ x,
                                                 f16* __restrict__ xh,
                                                 int nvalid, int npad) {
  int total = npad * 192;
  for (int idx = blockIdx.x * blockDim.x + threadIdx.x; idx < total;
       idx += gridDim.x * blockDim.x) {
    int row = idx / 192;
    f16x4 o;
    if (row < nvalid) {
      const float4 v = *(const float4*)(x + (size_t)idx * 4);
      o[0] = (f16)v.x; o[1] = (f16)v.y; o[2] = (f16)v.z; o[3] = (f16)v.w;
    } else {
      o[0] = (f16)0.f; o[1] = (f16)0.f; o[2] = (f16)0.f; o[3] = (f16)0.f;
    }
    *(f16x4*)(xh + (size_t)idx * 4) = o;
  }
}

// ---------------- both W [768][768] f32 -> Wt [n][k] f16, one launch ----------------
__global__ __launch_bounds__(256) void k_transpose_w2(const float* __restrict__ W1,
                                                      const float* __restrict__ W2,
                                                      f16* __restrict__ Wt1,
                                                      f16* __restrict__ Wt2) {
  const float* W = blockIdx.z ? W2 : W1;
  f16* Wt = blockIdx.z ? Wt2 : Wt1;
  __shared__ float tile[32][33];
  int bn = blockIdx.x * 32;
  int bk = blockIdx.y * 32;
  int tx = threadIdx.x & 31, ty = threadIdx.x >> 5;
  #pragma unroll
  for (int r = ty; r < 32; r += 8)
    tile[r][tx] = W[(size_t)(bk + r) * 768 + bn + tx];
  __syncthreads();
  #pragma unroll
  for (int r = ty; r < 32; r += 8)
    Wt[(size_t)(bn + r) * 768 + bk + tx] = (f16)tile[tx][r];
}

// ---------------- CSR build ----------------
__global__ void k_hist(const int* __restrict__ dst, int E, int* __restrict__ counts) {
  for (int e = blockIdx.x * blockDim.x + threadIdx.x; e < E;
       e += gridDim.x * blockDim.x) atomicAdd(&counts[dst[e]], 1);
}

__global__ __launch_bounds__(1024) void k_scan_block(const int* __restrict__ counts,
                                                     int* __restrict__ starts,
                                                     int* __restrict__ cursor, int n) {
  const int t = threadIdx.x;
  const int nthr = 1024;
  const int chunk = (n + nthr - 1) / nthr;
  const int base = t * chunk;
  int tsum = 0;
  for (int i = 0; i < chunk; i++) {
    int idx = base + i;
    if (idx < n) tsum += counts[idx];
  }
  int lane = t & 63, wv = t >> 6;
  int s = tsum;
  #pragma unroll
  for (int off = 1; off < 64; off <<= 1) {
    int tmp = __shfl_up(s, off);
    if (lane >= off) s += tmp;
  }
  __shared__ int wsum[16];
  if (lane == 63) wsum[wv] = s;
  __syncthreads();
  int woff = 0;
  for (int w = 0; w < wv; w++) woff += wsum[w];
  int run = woff + s - tsum;
  for (int i = 0; i < chunk; i++) {
    int idx = base + i;
    if (idx < n) {
      starts[idx] = run;
      cursor[idx] = run;
      run += counts[idx];
    }
  }
  if (t == nthr - 1) starts[n] = run;
}

__global__ void k_fill(const int* __restrict__ src, const int* __restrict__ dst, int E,
                       int* __restrict__ cursor, int* __restrict__ src_sorted) {
  for (int e = blockIdx.x * blockDim.x + threadIdx.x; e < E;
       e += gridDim.x * blockDim.x) {
    int slot = atomicAdd(&cursor[dst[e]], 1);
    src_sorted[slot] = src[e];
  }
}

// ---------------- fp16 MFMA GEMM, BK=64, global_load_lds staging ----------------
// LDS per matrix: 128 rows x 64 f16 (128 B/row = 8 chunks of 8 f16).
// Swizzle: phys_chunk = logical_chunk ^ (row & 7)  -> fragment reads hit all 32
// banks at 2 lanes/bank (free). Staging: linear LDS dest (GLL16), pre-swizzled
// global source (rule #21). Halves barrier drains vs BK=32.
__global__ __launch_bounds__(256) void k_gemm_f16(const f16* __restrict__ A,
                                                  const f16* __restrict__ Bt,
                                                  f16* __restrict__ C, int Mvalid) {
  __shared__ __align__(16) f16 As[8192];  // 128*64
  __shared__ __align__(16) f16 Bs[8192];
  const int K = 768;
  const int tid = threadIdx.x;
  const int bm = blockIdx.x * 128;
  const int bn = blockIdx.y * 128;
  const int lane = tid & 63;
  const int wave = tid >> 6;
  const int wr = (wave >> 1) * 64;
  const int wc = (wave & 1) * 64;

  // staging: pass p (0..3), cell = p*256 + tid; row = cell>>3, phys = cell&7,
  // logical chunk = phys ^ (row&7); LDS dest base (f16 units) = p*2048 + wave*512.
  size_t goffA[4], goffB[4];
  #pragma unroll
  for (int p = 0; p < 4; p++) {
    const int cell = p * 256 + tid;
    const int row = cell >> 3;
    const int cl = (cell & 7) ^ (row & 7);
    goffA[p] = (size_t)(bm + row) * K + cl * 8;
    goffB[p] = (size_t)(bn + row) * K + cl * 8;
  }

  f32x4 acc[4][4];
  const f32x4 vzero = {0.f, 0.f, 0.f, 0.f};
  #pragma unroll
  for (int i = 0; i < 4; i++)
    #pragma unroll
    for (int j = 0; j < 4; j++) acc[i][j] = vzero;

  const int fr = lane & 15;
  const int fq = lane >> 4;

  for (int k0 = 0; k0 < K; k0 += 64) {
    #pragma unroll
    for (int p = 0; p < 4; p++) GLL16(A + goffA[p] + k0, As + p * 2048 + wave * 512);
    #pragma unroll
    for (int p = 0; p < 4; p++) GLL16(Bt + goffB[p] + k0, Bs + p * 2048 + wave * 512);
    __syncthreads();
    #pragma unroll
    for (int ks = 0; ks < 2; ks++) {
      f16x8 af[4], bf[4];
      #pragma unroll
      for (int i = 0; i < 4; i++) {
        const int r = wr + i * 16 + fr;
        const int phys = (ks * 4 + fq) ^ (r & 7);
        af[i] = *(const f16x8*)(&As[r * 64 + phys * 8]);
      }
      #pragma unroll
      for (int j = 0; j < 4; j++) {
        const int r = wc + j * 16 + fr;
        const int phys = (ks * 4 + fq) ^ (r & 7);
        bf[j] = *(const f16x8*)(&Bs[r * 64 + phys * 8]);
      }
      #pragma unroll
      for (int i = 0; i < 4; i++)
        #pragma unroll
        for (int j = 0; j < 4; j++)
          acc[i][j] = __builtin_amdgcn_mfma_f32_16x16x32_f16(af[i], bf[j], acc[i][j], 0, 0, 0);
    }
    __syncthreads();
  }

  #pragma unroll
  for (int i = 0; i < 4; i++) {
    #pragma unroll
    for (int j = 0; j < 4; j++) {
      const int col = bn + wc + j * 16 + fr;
      #pragma unroll
      for (int r = 0; r < 4; r++) {
        const int row = bm + wr + i * 16 + fq * 4 + r;
        if (row < Mvalid) C[(size_t)row * 768 + col] = (f16)acc[i][j][r];
      }
    }
  }
}

// ---------------- attention logits: al[n][h] = sum_c h[n][h*C+c]*a[h][c] ----------------
template <int H>
__global__ __launch_bounds__(256) void k_al(const f16* __restrict__ h,
                                            const float* __restrict__ a_src,
                                            const float* __restrict__ a_dst,
                                            float* __restrict__ als,
                                            float* __restrict__ ald, int N) {
  int node = blockIdx.x * 4 + (threadIdx.x >> 6);
  int lane = threadIdx.x & 63;
  if (node >= N) return;
  const f16x4* hp = (const f16x4*)(h + (size_t)node * 768 + lane * 12);
  float ss = 0.f, sd = 0.f;
  int cbase = lane * 12;
  #pragma unroll
  for (int q = 0; q < 3; q++) {
    f16x4 hv = hp[q];
    #pragma unroll
    for (int j = 0; j < 4; j++) {
      int c = cbase + q * 4 + j;
      float v = (float)hv[j];
      ss += v * a_src[c];
      sd += v * a_dst[c];
    }
  }
  const int red = (H == 8) ? 8 : 64;
  #pragma unroll
  for (int off = 1; off < red; off <<= 1) {
    ss += __shfl_xor(ss, off);
    sd += __shfl_xor(sd, off);
  }
  if (H == 8) {
    if ((lane & 7) == 0) {
      als[(size_t)node * 8 + (lane >> 3)] = ss;
      ald[(size_t)node * 8 + (lane >> 3)] = sd;
    }
  } else {
    if (lane == 0) { als[node] = ss; ald[node] = sd; }
  }
}

// ---------------- fused segment softmax + aggregation + bias (+ELU) ----------------
// proven structure (73.5us): 192 threads, coalesced full-row gather, LDS alphas.
template <int H, bool FINAL>
__global__ __launch_bounds__(192) void k_aggregate(
    const f16* __restrict__ h, const float* __restrict__ als,
    const float* __restrict__ ald, const int* __restrict__ starts,
    const int* __restrict__ src_sorted, const float* __restrict__ bias,
    void* __restrict__ outv, int nvalid) {
  const int n = blockIdx.x;
  const int t = threadIdx.x;
  if (n >= nvalid) return;
  __shared__ float s_ex[256 * H];
  __shared__ int s_src[256];
  __shared__ float s_zp[3][H];
  const int start = starts[n];
  const int deg = starts[n + 1] - start;
  const int lane = t & 63, wv = t >> 6;
  const int hA = (H == 8) ? (t & 7) : 0;
  const int myh = (H == 8) ? (t / 24) : 0;
  const float ald_A = ald[(size_t)n * H + hA];

  float zpart = 0.f;
  float4 acc = {0.f, 0.f, 0.f, 0.f};

  for (int cb = 0; cb < deg; cb += 256) {
    const int cnt = min(256, deg - cb);
    for (int idx = t; idx < cnt * H; idx += 192) {
      const int e = (H == 8) ? (idx >> 3) : idx;
      const int s = src_sorted[start + cb + e];
      if (H == 1 || (idx & 7) == 0) s_src[e] = s;
      float v = als[(size_t)s * H + hA] + ald_A;
      v = v > 0.f ? v : LRELU_SLOPE * v;
      const float ex = __expf(v);
      s_ex[idx] = ex;
      zpart += ex;
    }
    __syncthreads();
    for (int e = 0; e < cnt; e++) {
      const f16x4 hv = *(const f16x4*)(h + (size_t)s_src[e] * 768 + 4 * t);
      const float a = s_ex[e * H + myh];
      acc.x += a * (float)hv[0];
      acc.y += a * (float)hv[1];
      acc.z += a * (float)hv[2];
      acc.w += a * (float)hv[3];
    }
    __syncthreads();
  }

  if (H == 8) {
    #pragma unroll
    for (int off = 8; off < 64; off <<= 1) zpart += __shfl_xor(zpart, off);
    if (lane < 8) s_zp[wv][lane] = zpart;
  } else {
    #pragma unroll
    for (int off = 1; off < 64; off <<= 1) zpart += __shfl_xor(zpart, off);
    if (lane == 0) s_zp[wv][0] = zpart;
  }
  __syncthreads();
  const float z = s_zp[0][myh] + s_zp[1][myh] + s_zp[2][myh];
  const float inv = 1.f / (z + 1e-16f);

  const float4 bv = *(const float4*)(bias + 4 * t);
  float v0 = acc.x * inv + bv.x;
  float v1 = acc.y * inv + bv.y;
  float v2 = acc.z * inv + bv.z;
  float v3 = acc.w * inv + bv.w;
  if (!FINAL) {
    v0 = v0 > 0.f ? v0 : expm1f(v0);
    v1 = v1 > 0.f ? v1 : expm1f(v1);
    v2 = v2 > 0.f ? v2 : expm1f(v2);
    v3 = v3 > 0.f ? v3 : expm1f(v3);
    f16x4 o;
    o[0] = (f16)v0; o[1] = (f16)v1; o[2] = (f16)v2; o[3] = (f16)v3;
    *(f16x4*)((f16*)outv + (size_t)n * 768 + 4 * t) = o;
  } else {
    float4 o = {v0, v1, v2, v3};
    *(float4*)((float*)outv + (size_t)n * 768 + 4 * t) = o;
  }
}

// ---------------- launcher ----------------
extern "C" void kernel_launch(void* const* d_in, const int* in_sizes, int n_in,
                              void* d_out, int out_size, void* d_ws, size_t ws_size,
                              hipStream_t stream) {
  const float* x   = (const float*)d_in[0];
  const int*   ei  = (const int*)d_in[1];
  const float* W1  = (const float*)d_in[2];
  const float* as1 = (const float*)d_in[3];
  const float* ad1 = (const float*)d_in[4];
  const float* b1  = (const float*)d_in[5];
  const float* W2  = (const float*)d_in[6];
  const float* as2 = (const float*)d_in[7];
  const float* ad2 = (const float*)d_in[8];
  const float* b2  = (const float*)d_in[9];

  const int N = in_sizes[0] / 768;
  const int E = in_sizes[1] / 2;
  const int Mpad = (N + 127) & ~127;
  const int* srcp = ei;
  const int* dstp = ei + E;

  char* p = (char*)d_ws;
  auto alloc = [&](size_t b) { char* r = p; p += (b + 255) & ~(size_t)255; return r; };
  f16*   bufX   = (f16*)alloc((size_t)Mpad * 768 * sizeof(f16));  // x_h, then out1
  f16*   bufH   = (f16*)alloc((size_t)Mpad * 768 * sizeof(f16));  // h1, then h2
  f16*   Wt1    = (f16*)alloc((size_t)768 * 768 * sizeof(f16));
  f16*   Wt2    = (f16*)alloc((size_t)768 * 768 * sizeof(f16));
  float* als1   = (float*)alloc((size_t)N * 8 * sizeof(float));
  float* ald1   = (float*)alloc((size_t)N * 8 * sizeof(float));
  float* als2   = (float*)alloc((size_t)N * sizeof(float));
  float* ald2   = (float*)alloc((size_t)N * sizeof(float));
  int*   counts = (int*)alloc((size_t)N * sizeof(int));
  int*   starts = (int*)alloc(((size_t)N + 1) * sizeof(int));
  int*   cursor = (int*)alloc((size_t)N * sizeof(int));
  int*   srcs   = (int*)alloc((size_t)E * sizeof(int));

  // CSR build
  hipMemsetAsync(counts, 0, (size_t)N * sizeof(int), stream);
  k_hist<<<dim3(512), dim3(256), 0, stream>>>(dstp, E, counts);
  k_scan_block<<<dim3(1), dim3(1024), 0, stream>>>(counts, starts, cursor, N);
  k_fill<<<dim3(512), dim3(256), 0, stream>>>(srcp, dstp, E, cursor, srcs);

  // prep
  k_prep_xh<<<dim3(1024), dim3(256), 0, stream>>>(x, bufX, N, Mpad);
  k_transpose_w2<<<dim3(24, 24, 2), dim3(256), 0, stream>>>(W1, W2, Wt1, Wt2);

  // layer 1
  k_gemm_f16<<<dim3(Mpad / 128, 6), dim3(256), 0, stream>>>(bufX, Wt1, bufH, N);
  k_al<8><<<dim3((N + 3) / 4), dim3(256), 0, stream>>>(bufH, as1, ad1, als1, ald1, N);
  k_aggregate<8, false><<<dim3(N), dim3(192), 0, stream>>>(bufH, als1, ald1, starts, srcs, b1, bufX, N);

  // layer 2
  k_gemm_f16<<<dim3(Mpad / 128, 6), dim3(256), 0, stream>>>(bufX, Wt2, bufH, N);
  k_al<1><<<dim3((N + 3) / 4), dim3(256), 0, stream>>>(bufH, as2, ad2, als2, ald2, N);
  k_aggregate<1, true><<<dim3(N), dim3(192), 0, stream>>>(bufH, als2, ald2, starts, srcs, b2, d_out, N);
}